// Round 1
// baseline (80.382 us; speedup 1.0000x reference)
//
#include <hip/hip_runtime.h>

// Max-unpool 2x2: input x[B=16,H=128,W=128,C=64] f32, indices int32 encoding
// per-batch flat position ((2h+dy)*Wout + (2w+dx))*C + c in output
// [B,Hout=256,Wout=256,C=64]. Each input element lands in its own disjoint
// 2x2 window -> no collisions. One thread owns one window x 4 channels:
// writes 4 float4 stores (value where idx matches, else zero). Covers every
// output element exactly once -> no zero-init pass, no atomics.

__global__ __launch_bounds__(256) void unpool_window_kernel(
    const float4* __restrict__ x,
    const int4*  __restrict__ ind,
    float4*      __restrict__ out,
    int nvec)
{
    int t = blockIdx.x * blockDim.x + threadIdx.x;
    if (t >= nvec) return;

    float4 v  = x[t];
    int4   id = ind[t];

    int e = t << 2;              // first element index (4 consecutive channels)
    int c = e & 63;              // channel (multiple of 4)
    int w = (e >> 6)  & 127;
    int h = (e >> 13) & 127;
    int b =  e >> 20;

    // within-batch output element offset of (row=2h, col=2w, chan=c)
    int pos00 = (h << 15) | (w << 7) | c;   // 2h*Wout*C = h<<15 ; 2w*C = w<<7
    size_t base = ((size_t)b << 22) + (size_t)pos00;  // Hout*Wout*C = 1<<22

    // candidate positions for the 4 channels in each of the 4 window slots
    int p00 = pos00;            // (2h,   2w  )
    int p01 = pos00 + 64;       // (2h,   2w+1)   +C
    int p10 = pos00 + 16384;    // (2h+1, 2w  )   +Wout*C
    int p11 = pos00 + 16448;    // (2h+1, 2w+1)

    float4 s00, s01, s10, s11;
    s00.x = (id.x == p00 + 0) ? v.x : 0.0f;
    s00.y = (id.y == p00 + 1) ? v.y : 0.0f;
    s00.z = (id.z == p00 + 2) ? v.z : 0.0f;
    s00.w = (id.w == p00 + 3) ? v.w : 0.0f;

    s01.x = (id.x == p01 + 0) ? v.x : 0.0f;
    s01.y = (id.y == p01 + 1) ? v.y : 0.0f;
    s01.z = (id.z == p01 + 2) ? v.z : 0.0f;
    s01.w = (id.w == p01 + 3) ? v.w : 0.0f;

    s10.x = (id.x == p10 + 0) ? v.x : 0.0f;
    s10.y = (id.y == p10 + 1) ? v.y : 0.0f;
    s10.z = (id.z == p10 + 2) ? v.z : 0.0f;
    s10.w = (id.w == p10 + 3) ? v.w : 0.0f;

    s11.x = (id.x == p11 + 0) ? v.x : 0.0f;
    s11.y = (id.y == p11 + 1) ? v.y : 0.0f;
    s11.z = (id.z == p11 + 2) ? v.z : 0.0f;
    s11.w = (id.w == p11 + 3) ? v.w : 0.0f;

    float4* o = out + (base >> 2);
    o[0]    = s00;   // (2h,   2w  , c..c+3)
    o[16]   = s01;   // +64 floats
    o[4096] = s10;   // +16384 floats
    o[4112] = s11;
}

extern "C" void kernel_launch(void* const* d_in, const int* in_sizes, int n_in,
                              void* d_out, int out_size, void* d_ws, size_t ws_size,
                              hipStream_t stream) {
    const float4* x   = (const float4*)d_in[0];
    const int4*   ind = (const int4*)d_in[1];
    float4*       out = (float4*)d_out;

    int n_elems = in_sizes[0];          // B*H*W*C = 16,777,216
    int nvec    = n_elems >> 2;         // 4,194,304 threads
    int block   = 256;
    int grid    = (nvec + block - 1) / block;  // 16384

    unpool_window_kernel<<<grid, block, 0, stream>>>(x, ind, out, nvec);
}

// Round 3
// 70.673 us; speedup vs baseline: 1.1374x; 1.1374x over previous
//
#include <hip/hip_runtime.h>

// Max-unpool 2x2: x[B=16,H=128,W=128,C=64] f32, indices int32 encoding
// per-batch flat position ((2h+dy)*Wout + (2w+dx))*C + c in output
// [B,Hout=256,Wout=256,C=64]. Each input element lands in its own disjoint
// 2x2 window -> no collisions. One thread owns one window x 4 channels:
// 4 float4 stores (value where idx matches, else zero). Covers every output
// element exactly once -> no zero-init pass, no atomics.
//
// R1: all streams pure streaming (448 MB vs 32 MB L2) -> nontemporal
// loads/stores to avoid L2 allocation/pollution.
// R2: __builtin_nontemporal_* needs native clang vectors, not HIP_vector_type.

typedef float f32x4 __attribute__((ext_vector_type(4)));
typedef int   i32x4 __attribute__((ext_vector_type(4)));

__global__ __launch_bounds__(256) void unpool_window_kernel(
    const f32x4* __restrict__ x,
    const i32x4* __restrict__ ind,
    f32x4*       __restrict__ out,
    int nvec)
{
    int t = blockIdx.x * blockDim.x + threadIdx.x;
    if (t >= nvec) return;

    f32x4 v  = __builtin_nontemporal_load(&x[t]);
    i32x4 id = __builtin_nontemporal_load(&ind[t]);

    int e = t << 2;              // first element index (4 consecutive channels)
    int c = e & 63;              // channel (multiple of 4)
    int w = (e >> 6)  & 127;
    int h = (e >> 13) & 127;
    int b =  e >> 20;

    // within-batch output element offset of (row=2h, col=2w, chan=c)
    int pos00 = (h << 15) | (w << 7) | c;   // 2h*Wout*C = h<<15 ; 2w*C = w<<7
    size_t base = ((size_t)b << 22) + (size_t)pos00;  // Hout*Wout*C = 1<<22

    int p00 = pos00;            // (2h,   2w  )
    int p01 = pos00 + 64;       // (2h,   2w+1)   +C
    int p10 = pos00 + 16384;    // (2h+1, 2w  )   +Wout*C
    int p11 = pos00 + 16448;    // (2h+1, 2w+1)

    i32x4 cc = {p00 + 0, p00 + 1, p00 + 2, p00 + 3};

    f32x4 s00, s01, s10, s11;
    s00.x = (id.x == cc.x) ? v.x : 0.0f;
    s00.y = (id.y == cc.y) ? v.y : 0.0f;
    s00.z = (id.z == cc.z) ? v.z : 0.0f;
    s00.w = (id.w == cc.w) ? v.w : 0.0f;

    s01.x = (id.x == cc.x + 64) ? v.x : 0.0f;
    s01.y = (id.y == cc.y + 64) ? v.y : 0.0f;
    s01.z = (id.z == cc.z + 64) ? v.z : 0.0f;
    s01.w = (id.w == cc.w + 64) ? v.w : 0.0f;

    s10.x = (id.x == cc.x + 16384) ? v.x : 0.0f;
    s10.y = (id.y == cc.y + 16384) ? v.y : 0.0f;
    s10.z = (id.z == cc.z + 16384) ? v.z : 0.0f;
    s10.w = (id.w == cc.w + 16384) ? v.w : 0.0f;

    s11.x = (id.x == cc.x + 16448) ? v.x : 0.0f;
    s11.y = (id.y == cc.y + 16448) ? v.y : 0.0f;
    s11.z = (id.z == cc.z + 16448) ? v.z : 0.0f;
    s11.w = (id.w == cc.w + 16448) ? v.w : 0.0f;

    f32x4* o = out + (base >> 2);
    __builtin_nontemporal_store(s00, &o[0]);     // (2h,   2w  , c..c+3)
    __builtin_nontemporal_store(s01, &o[16]);    // +64 floats
    __builtin_nontemporal_store(s10, &o[4096]);  // +16384 floats
    __builtin_nontemporal_store(s11, &o[4112]);
}

extern "C" void kernel_launch(void* const* d_in, const int* in_sizes, int n_in,
                              void* d_out, int out_size, void* d_ws, size_t ws_size,
                              hipStream_t stream) {
    const f32x4* x   = (const f32x4*)d_in[0];
    const i32x4* ind = (const i32x4*)d_in[1];
    f32x4*       out = (f32x4*)d_out;

    int n_elems = in_sizes[0];          // B*H*W*C = 16,777,216
    int nvec    = n_elems >> 2;         // 4,194,304 threads
    int block   = 256;
    int grid    = (nvec + block - 1) / block;  // 16384

    unpool_window_kernel<<<grid, block, 0, stream>>>(x, ind, out, nvec);
}